// Round 3
// baseline (1692.503 us; speedup 1.0000x reference)
//
#include <hip/hip_runtime.h>

// out[b,h] = x[b]·W[h] + bias[h]; result[b] = sum_h out[b,h]*vconf[b,h]
// B=131072, DIM=1024, NH=21. d_out = [result (B) | out (B*NH)] fp32.
//
// R3: register-double-buffered LDS pipeline with PLAIN vector loads (compiler
// emits precise vmcnt -- no DMA aliasing conservatism, no scalar-W SGPR
// thrash). Block=256 (4 waves), tile=256 rows, BK=32 floats.
// Lane owns rows {lane+64k}; wave owns 6 heads (21 padded to 24, masked).

#define B_ROWS 131072
#define DIM    1024
#define NH     21
#define NHP    24            // 4 waves x 6 heads
#define HPW    6
#define BK     32            // floats per K-chunk (128 B/row)
#define NCH    (DIM / BK)    // 32 chunks
#define TILE   256
#define BLOCK  256
#define XSTR   36            // x LDS row stride (floats): 16B-aligned, 4-bank rotate/row

__global__ __launch_bounds__(BLOCK, 2) void linmodel_kernel(
    const float* __restrict__ x,      // [B, DIM]
    const float* __restrict__ vconf,  // [B, NH]
    const float* __restrict__ W,      // [NH, DIM]
    const float* __restrict__ bias,   // [NH]
    float* __restrict__ result,       // [B]
    float* __restrict__ out)          // [B, NH]
{
    __shared__ float xs[TILE * XSTR];   // 36864 B
    __shared__ float ws[NHP * BK];      //  3072 B

    const int  t    = threadIdx.x;
    const int  wave = t >> 6;
    const int  lane = t & 63;
    const long base = (long)blockIdx.x * TILE;
    const int  hbase = wave * HPW;      // 0,6,12,18

    // ---- staging coordinates (thread t stages 8 x-float4s + <=1 W-float4) ----
    const int srow = t >> 3;            // 0..31 (+32j)
    const int sc4  = (t & 7) << 2;      // float offset within 32-float chunk row
    const float* xsrc = x + (base + srow) * DIM + sc4;
    float*       xdst = xs + srow * XSTR + sc4;

    const int  wh   = t >> 3;           // 0..31 (only t<192 used)
    const bool wld  = (t < NHP * 8) && (wh < NH);
    const bool wst  = (t < NHP * 8);
    const float* wsrc = W + (long)wh * DIM + sc4;
    float*       wdst = ws + wh * BK + sc4;

    float4 nx[8];
    float4 nw;

    auto LOADX = [&](int c) {
#pragma unroll
        for (int j = 0; j < 8; ++j)
            nx[j] = *(const float4*)(xsrc + (long)(32 * j) * DIM + c * BK);
    };
    auto LOADW = [&](int c) {
        nw = wld ? *(const float4*)(wsrc + c * BK) : make_float4(0.f, 0.f, 0.f, 0.f);
    };
    auto WRITEX = [&]() {
#pragma unroll
        for (int j = 0; j < 8; ++j)
            *(float4*)(xdst + 32 * j * XSTR) = nx[j];
    };
    auto WRITEW = [&]() { if (wst) *(float4*)wdst = nw; };

    // ---- prologue: chunk 0 to LDS, chunk 1 in flight ----
    LOADX(0); LOADW(0);
    WRITEX(); WRITEW();
    __syncthreads();
    LOADX(1); LOADW(1);

    float acc[4][HPW];
#pragma unroll
    for (int k = 0; k < 4; ++k)
#pragma unroll
        for (int h = 0; h < HPW; ++h) acc[k][h] = 0.f;

#pragma unroll 1
    for (int c = 0; c < NCH; ++c) {
        // compute chunk c from LDS
#pragma unroll
        for (int cg = 0; cg < 8; ++cg) {
            float4 xv[4];
#pragma unroll
            for (int k = 0; k < 4; ++k)
                xv[k] = *(const float4*)(xs + (lane + 64 * k) * XSTR + (cg << 2));
#pragma unroll
            for (int h = 0; h < HPW; ++h) {
                const float4 wv = *(const float4*)(ws + (hbase + h) * BK + (cg << 2));
#pragma unroll
                for (int k = 0; k < 4; ++k)
                    acc[k][h] = fmaf(xv[k].x, wv.x,
                                fmaf(xv[k].y, wv.y,
                                fmaf(xv[k].z, wv.z,
                                fmaf(xv[k].w, wv.w, acc[k][h]))));
            }
        }
        __syncthreads();                    // all waves done reading LDS
        if (c < NCH - 1) {
            WRITEX(); WRITEW();             // waits (precise vmcnt) on c+1 loads
            if (c < NCH - 2) { LOADX(c + 2); LOADW(c + 2); }
            __syncthreads();                // writes visible
        }
    }

    // ---- epilogue ----
    __syncthreads();                        // xs dead -> overlay psum
    float* psum = xs;                       // [4][TILE]

    float bv[HPW];
#pragma unroll
    for (int h = 0; h < HPW; ++h) {
        const int hg = hbase + h;
        bv[h] = (hg < NH) ? bias[hg] : 0.f;
    }

#pragma unroll
    for (int k = 0; k < 4; ++k) {
        const int  row  = lane + 64 * k;
        const long grow = base + row;
        float partial = 0.f;
#pragma unroll
        for (int h = 0; h < HPW; ++h) {
            const int hg = hbase + h;
            if (hg < NH) {                  // wave-uniform per (wave,h)
                const float o = acc[k][h] + bv[h];
                out[grow * NH + hg] = o;
                partial += o * vconf[grow * NH + hg];
            }
        }
        psum[wave * TILE + row] = partial;
    }
    __syncthreads();

    result[base + t] = psum[t] + psum[TILE + t] + psum[2 * TILE + t] + psum[3 * TILE + t];
}

extern "C" void kernel_launch(void* const* d_in, const int* in_sizes, int n_in,
                              void* d_out, int out_size, void* d_ws, size_t ws_size,
                              hipStream_t stream) {
    const float* x     = (const float*)d_in[0];
    const float* vconf = (const float*)d_in[1];
    const float* W     = (const float*)d_in[2];
    const float* bias  = (const float*)d_in[3];
    float* result = (float*)d_out;
    float* out    = (float*)d_out + B_ROWS;

    linmodel_kernel<<<dim3(B_ROWS / TILE), dim3(BLOCK), 0, stream>>>(
        x, vconf, W, bias, result, out);
}

// Round 4
// 746.005 us; speedup vs baseline: 2.2688x; 2.2688x over previous
//
#include <hip/hip_runtime.h>
#include <hip/hip_bf16.h>

// out[b,h] = x[b]·W[h] + bias[h]; result[b] = sum_h out[b,h]*vconf[b,h]
// B=131072, DIM=1024, NH=21. d_out = [result (B) | out (B*NH)] fp32.
//
// R4: MFMA 16x16x32 bf16. x streamed global->VGPR->bf16 frag (NO LDS, no
// K-loop barriers, depth-2 pipeline). W converted to bf16 LDS once (padded,
// zero row for heads>=21). Wave owns 32 rows; acc in AGPRs; tiny VGPR
// footprint so nothing can spill (R3's 2.28 GB scratch traffic).

#define B_ROWS 131072
#define DIM    1024
#define NH     21
#define NKS    (DIM / 32)     // 32 K-steps of 32
#define WSTR   1048           // LDS W row stride (bf16): 524 dwords = 12 mod 32
                              // -> B-frag bank group (3i+q)%8, all distinct

typedef __attribute__((ext_vector_type(8))) short  short8;  // 8 bf16 (4 VGPR)
typedef __attribute__((ext_vector_type(4))) float  f32x4;

__device__ __forceinline__ short8 cvt_bf16x8(const float4 a, const float4 b) {
    union { short8 v; __hip_bfloat16 h[8]; } u;
    u.h[0] = __float2bfloat16(a.x); u.h[1] = __float2bfloat16(a.y);
    u.h[2] = __float2bfloat16(a.z); u.h[3] = __float2bfloat16(a.w);
    u.h[4] = __float2bfloat16(b.x); u.h[5] = __float2bfloat16(b.y);
    u.h[6] = __float2bfloat16(b.z); u.h[7] = __float2bfloat16(b.w);
    return u.v;
}

__global__ __launch_bounds__(256) void linmodel_kernel(
    const float* __restrict__ x,      // [B, DIM]
    const float* __restrict__ vconf,  // [B, NH]
    const float* __restrict__ W,      // [NH, DIM]
    const float* __restrict__ bias,   // [NH]
    float* __restrict__ result,       // [B]
    float* __restrict__ out)          // [B, NH]
{
    __shared__ __hip_bfloat16 ws[22 * WSTR];   // 46.1 KB; row 21 = zeros

    const int t = threadIdx.x;

    // ---- stage W fp32 -> bf16 LDS (once; W is L2-hot across blocks) ----
    for (int idx = t * 4; idx < NH * DIM; idx += 256 * 4) {
        const int r = idx >> 10;
        const int c = idx & 1023;
        const float4 w = *(const float4*)(W + r * DIM + c);
        union { ushort4 u4; __hip_bfloat16 h[4]; } u;
        u.h[0] = __float2bfloat16(w.x); u.h[1] = __float2bfloat16(w.y);
        u.h[2] = __float2bfloat16(w.z); u.h[3] = __float2bfloat16(w.w);
        *(ushort4*)(ws + r * WSTR + c) = u.u4;
    }
    if (t < 256) {  // zero row 21 (only cols < 1024 are ever read)
        const int c = t * 4;
        ushort4 z; z.x = z.y = z.z = z.w = 0;
        *(ushort4*)(ws + 21 * WSTR + c) = z;
    }
    __syncthreads();

    const int wave = t >> 6;
    const int lane = t & 63;
    const int n    = lane & 15;          // MFMA col / A row index
    const int q    = lane >> 4;          // k-quad / C row-group
    const long wavebase = (long)blockIdx.x * 128 + wave * 32;

    // A-frag source pointers: row = wavebase + 16a + n, cols q*8 + [0..7]
    const float* pa0 = x + (wavebase + n) * DIM + q * 8;
    const float* pa1 = pa0 + 16 * DIM;

    const int hb0 = n;                                   // B tile 0 head
    const int hb1 = (16 + n < NH) ? (16 + n) : NH;       // tile 1; NH -> zero row
    const __hip_bfloat16* pb0 = ws + hb0 * WSTR + q * 8;
    const __hip_bfloat16* pb1 = ws + hb1 * WSTR + q * 8;

    f32x4 acc00 = {0.f, 0.f, 0.f, 0.f}, acc01 = {0.f, 0.f, 0.f, 0.f};
    f32x4 acc10 = {0.f, 0.f, 0.f, 0.f}, acc11 = {0.f, 0.f, 0.f, 0.f};

    float4 xb[2][2][2];  // [buf][atile][half]
#define LOADK(buf, ks)                                              \
    {                                                               \
        xb[buf][0][0] = *(const float4*)(pa0 + (ks) * 32);          \
        xb[buf][0][1] = *(const float4*)(pa0 + (ks) * 32 + 4);      \
        xb[buf][1][0] = *(const float4*)(pa1 + (ks) * 32);          \
        xb[buf][1][1] = *(const float4*)(pa1 + (ks) * 32 + 4);      \
    }

    LOADK(0, 0)
    LOADK(1, 1)

#pragma unroll
    for (int ks = 0; ks < NKS; ++ks) {
        const int buf = ks & 1;
        const short8 af0 = cvt_bf16x8(xb[buf][0][0], xb[buf][0][1]);
        const short8 af1 = cvt_bf16x8(xb[buf][1][0], xb[buf][1][1]);
        if (ks + 2 < NKS) LOADK(buf, ks + 2)   // depth-2 prefetch
        const short8 bf0 = *(const short8*)(pb0 + ks * 32);
        const short8 bf1 = *(const short8*)(pb1 + ks * 32);
        acc00 = __builtin_amdgcn_mfma_f32_16x16x32_bf16(af0, bf0, acc00, 0, 0, 0);
        acc01 = __builtin_amdgcn_mfma_f32_16x16x32_bf16(af0, bf1, acc01, 0, 0, 0);
        acc10 = __builtin_amdgcn_mfma_f32_16x16x32_bf16(af1, bf0, acc10, 0, 0, 0);
        acc11 = __builtin_amdgcn_mfma_f32_16x16x32_bf16(af1, bf1, acc11, 0, 0, 0);
    }
#undef LOADK

    // ---- epilogue: C/D layout col=n, row=4q+reg ----
    const float bv0 = bias[n];                               // n < 16 < 21 valid
    const bool  h1ok = (16 + n) < NH;
    const float bv1 = h1ok ? bias[16 + n] : 0.f;

#pragma unroll
    for (int a = 0; a < 2; ++a) {
        const f32x4 c0 = a ? acc10 : acc00;
        const f32x4 c1 = a ? acc11 : acc01;
        float pr[4];
#pragma unroll
        for (int reg = 0; reg < 4; ++reg) {
            const long grow = wavebase + 16 * a + 4 * q + reg;
            float p = 0.f;
            {   // tile b=0: h = n (always valid)
                const float o = c0[reg] + bv0;
                out[grow * NH + n] = o;
                p += o * vconf[grow * NH + n];
            }
            if (h1ok) {  // tile b=1: h = 16+n
                const float o = c1[reg] + bv1;
                out[grow * NH + 16 + n] = o;
                p += o * vconf[grow * NH + 16 + n];
            }
            pr[reg] = p;
        }
        // reduce across the 16 lanes (n) of this row-group q
#pragma unroll
        for (int m = 1; m < 16; m <<= 1) {
#pragma unroll
            for (int reg = 0; reg < 4; ++reg)
                pr[reg] += __shfl_xor(pr[reg], m, 64);
        }
        const float rv = (n == 0) ? pr[0] : (n == 1) ? pr[1]
                       : (n == 2) ? pr[2] : pr[3];
        if (n < 4)
            result[wavebase + 16 * a + 4 * q + n] = rv;
    }
}

extern "C" void kernel_launch(void* const* d_in, const int* in_sizes, int n_in,
                              void* d_out, int out_size, void* d_ws, size_t ws_size,
                              hipStream_t stream) {
    const float* x     = (const float*)d_in[0];
    const float* vconf = (const float*)d_in[1];
    const float* W     = (const float*)d_in[2];
    const float* bias  = (const float*)d_in[3];
    float* result = (float*)d_out;
    float* out    = (float*)d_out + B_ROWS;

    linmodel_kernel<<<dim3(B_ROWS / 128), dim3(256), 0, stream>>>(
        x, vconf, W, bias, result, out);
}